// Round 2
// baseline (441.634 us; speedup 1.0000x reference)
//
#include <hip/hip_runtime.h>

typedef unsigned short ushort_t;
typedef unsigned int uint_t;
typedef __attribute__((ext_vector_type(8))) short bf16x8;
typedef __attribute__((ext_vector_type(4))) float floatx4;

#define ZDIM 32
#define KDIM 4
#define HDIM 128
#define B_TOTAL 32768
#define TB 32

// ws layout (ushort element offsets): Wd hi/lo reordered [k][n][c], Wsm hi/lo [m][n][c]
#define WS_WDH 0
#define WS_WDL 524288
#define WS_SMH 1048576
#define WS_SML 1097728

// LDS layout (byte offsets)
#define D_PITCH   1028        // fp32 elements per batch row (1024 + 4 stagger)
#define SH_D_OFF  0           // float [32][1028] = 131584 B
#define AUX_PITCH 132
#define SH_AUX_OFF 0          // float [3][32][132] = 50688 B (pre-loop only, aliases D)
#define SH_HH_OFF 51200       // ushort [32][136] = 8704 B (pre-loop only, aliases D)
#define SH_HL_OFF 59904       // ushort [32][136] = 8704 B (pre-loop only, aliases D)
#define SH_Z_OFF  131584      // float [32][36] = 4608 B
#define SH_T_OFF  136192      // float [32][36] = 4608 B
#define LDS_BYTES 140800

__device__ __forceinline__ ushort_t f2bf(float f) {
    uint_t u = __builtin_bit_cast(uint_t, f);
    u += 0x7FFFu + ((u >> 16) & 1u);
    return (ushort_t)(u >> 16);
}
__device__ __forceinline__ float bf2f(ushort_t s) {
    return __builtin_bit_cast(float, ((uint_t)s) << 16);
}
__device__ __forceinline__ void split1(float x, ushort_t& hi, ushort_t& lo) {
    hi = f2bf(x);
    lo = f2bf(x - bf2f(hi));
}
__device__ __forceinline__ void split4(float4 v, ushort4& hi, ushort4& lo) {
    split1(v.x, hi.x, lo.x); split1(v.y, hi.y, lo.y);
    split1(v.z, hi.z, lo.z); split1(v.w, hi.w, lo.w);
}
__device__ __forceinline__ float fast_tanh(float x) {
    float e = __expf(2.0f * x);
    return 1.0f - 2.0f / (e + 1.0f);
}

// ---------------------------------------------------------------------------
// Kernel 1: split Wd (reordered per-k-slice) and Wd1/Wd2/Wb into bf16 hi/lo.
// Work items are float4 chunks: Wd 131072, small 3*4096 = 12288 -> 560*256.
// ---------------------------------------------------------------------------
__global__ __launch_bounds__(256) void convert_kernel(
    const float* __restrict__ Wd, const float* __restrict__ Wd1,
    const float* __restrict__ Wd2, const float* __restrict__ Wb,
    ushort_t* __restrict__ ws)
{
    int g = blockIdx.x * 256 + threadIdx.x;
    if (g < 131072) {
        int k = g >> 15;            // 32768 float4 per k-slice
        int rem = g & 32767;
        int n = rem >> 5;           // n = i*32+j
        int c4 = rem & 31;
        float4 v = *((const float4*)Wd + (size_t)(4 * n + k) * 32 + c4);
        ushort4 hi, lo; split4(v, hi, lo);
        ((ushort4*)(ws + WS_WDH))[g] = hi;
        ((ushort4*)(ws + WS_WDL))[g] = lo;
    } else {
        int s = g - 131072;         // [0, 12288)
        const float* src = (s < 4096) ? Wd1 : ((s < 8192) ? Wd2 : Wb);
        int r = s & 4095;
        float4 v = ((const float4*)src)[r];
        ushort4 hi, lo; split4(v, hi, lo);
        ((ushort4*)(ws + WS_SMH))[s] = hi;
        ((ushort4*)(ws + WS_SML))[s] = lo;
    }
}

// ---------------------------------------------------------------------------
// Kernel 2: fused split-bf16 encoder GEMMs (fp32-accurate) + K-step flow.
// One WG = 32 batches; D kept fp32 in LDS.
// ---------------------------------------------------------------------------
__global__ __launch_bounds__(256, 1) void sylv_kernel(
    const ushort_t* __restrict__ wsb,
    const float* __restrict__ hglob,
    const float* __restrict__ z0,
    const float* __restrict__ bd,
    const float* __restrict__ bd1,
    const float* __restrict__ bd2,
    const float* __restrict__ bb,
    float* __restrict__ out)
{
    extern __shared__ char smem[];
    float*    sh_D   = (float*)(smem + SH_D_OFF);
    float*    sh_aux = (float*)(smem + SH_AUX_OFF);
    ushort_t* sh_hh  = (ushort_t*)(smem + SH_HH_OFF);
    ushort_t* sh_hl  = (ushort_t*)(smem + SH_HL_OFF);
    float*    sh_z   = (float*)(smem + SH_Z_OFF);
    float*    sh_t   = (float*)(smem + SH_T_OFF);

    const int t   = threadIdx.x;
    const int bg0 = blockIdx.x * TB;
    const int lane = t & 63, w = t >> 6;
    const int l15 = lane & 15, l4 = lane >> 4;
    const int jl = t & 7, b = t >> 3;

    // ---- stage h (fp32 -> bf16 hi/lo in LDS) and z0 ----
    {
        const float4* hsrc = (const float4*)(hglob + (size_t)bg0 * HDIM);
        #pragma unroll
        for (int it = 0; it < 4; ++it) {
            int c = t + it * 256;       // 1024 float4 chunks
            int row = c >> 5, col4 = c & 31;
            float4 v = hsrc[c];
            ushort4 hi, lo; split4(v, hi, lo);
            *(ushort4*)(sh_hh + row * 136 + col4 * 4) = hi;
            *(ushort4*)(sh_hl + row * 136 + col4 * 4) = lo;
        }
        float4 zv = *(const float4*)(z0 + (size_t)(bg0 + b) * ZDIM + jl * 4);
        *(float4*)(sh_z + b * 36 + jl * 4) = zv;
    }
    __syncthreads();

    // ---- A fragments (hi and lo): A[m=lane&15][k=(lane>>4)*8+j] ----
    bf16x8 ahi[2][4], alo[2][4];
    #pragma unroll
    for (int mt = 0; mt < 2; ++mt)
        #pragma unroll
        for (int kc = 0; kc < 4; ++kc) {
            ahi[mt][kc] = *(const bf16x8*)(sh_hh + (mt * 16 + l15) * 136 + kc * 32 + l4 * 8);
            alo[mt][kc] = *(const bf16x8*)(sh_hl + (mt * 16 + l15) * 136 + kc * 32 + l4 * 8);
        }

    // ---- small GEMMs (3-pass split): d1, d2, bpre -> aux[m][batch][n] ----
    #pragma unroll
    for (int pi = 0; pi < 6; ++pi) {
        int p = w * 6 + pi;
        int m_i = p >> 3, nt = p & 7, n = nt * 16 + l15;
        const ushort_t* wph = wsb + WS_SMH + (size_t)(m_i * 128 + n) * 128 + l4 * 8;
        const ushort_t* wpl = wsb + WS_SML + (size_t)(m_i * 128 + n) * 128 + l4 * 8;
        floatx4 a0 = {0.f, 0.f, 0.f, 0.f}, a1 = {0.f, 0.f, 0.f, 0.f};
        #pragma unroll
        for (int kc = 0; kc < 4; ++kc) {
            bf16x8 bh = *(const bf16x8*)(wph + kc * 32);
            bf16x8 bl = *(const bf16x8*)(wpl + kc * 32);
            a0 = __builtin_amdgcn_mfma_f32_16x16x32_bf16(ahi[0][kc], bh, a0, 0, 0, 0);
            a0 = __builtin_amdgcn_mfma_f32_16x16x32_bf16(alo[0][kc], bh, a0, 0, 0, 0);
            a0 = __builtin_amdgcn_mfma_f32_16x16x32_bf16(ahi[0][kc], bl, a0, 0, 0, 0);
            a1 = __builtin_amdgcn_mfma_f32_16x16x32_bf16(ahi[1][kc], bh, a1, 0, 0, 0);
            a1 = __builtin_amdgcn_mfma_f32_16x16x32_bf16(alo[1][kc], bh, a1, 0, 0, 0);
            a1 = __builtin_amdgcn_mfma_f32_16x16x32_bf16(ahi[1][kc], bl, a1, 0, 0, 0);
        }
        const float* bv = (m_i == 0) ? bd1 : ((m_i == 1) ? bd2 : bb);
        float bias = bv[n];
        float* ap = sh_aux + m_i * (32 * AUX_PITCH) + n;
        #pragma unroll
        for (int r = 0; r < 4; ++r) {
            float v0 = a0[r] + bias, v1 = a1[r] + bias;
            if (m_i < 2) { v0 = fast_tanh(v0); v1 = fast_tanh(v1); }
            ap[(l4 * 4 + r) * AUX_PITCH] = v0;
            ap[(16 + l4 * 4 + r) * AUX_PITCH] = v1;
        }
    }
    __syncthreads();

    // ---- aux -> registers (48 floats/thread), then free the D region ----
    float4 d1r[4], d2r[4], bpr[4];
    #pragma unroll
    for (int u = 0; u < 4; ++u) {
        int joff = (jl + 8 * u) * 4;
        d1r[u] = *(const float4*)(sh_aux + 0 * (32 * AUX_PITCH) + b * AUX_PITCH + joff);
        d2r[u] = *(const float4*)(sh_aux + 1 * (32 * AUX_PITCH) + b * AUX_PITCH + joff);
        bpr[u] = *(const float4*)(sh_aux + 2 * (32 * AUX_PITCH) + b * AUX_PITCH + joff);
    }
    __syncthreads();

    float ld_acc = 0.f;
    float* Drowf = sh_D + b * D_PITCH;
    const int jqa[4] = {jl, jl + 8, jl + 16, jl + 24};

    #pragma unroll
    for (int kk = 0; kk < KDIM; ++kk) {
        // ---- GEMM: D_k[b][n] = h@Wd_k^T + bd, fp32 via 3-pass split ----
        const size_t kbase = (size_t)(kk * 1024) * 128;
        #pragma unroll
        for (int g = 0; g < 8; ++g) {
            int n0 = (w * 16 + 2 * g) * 16 + l15;
            int n1 = n0 + 16;
            const ushort_t* w0h = wsb + WS_WDH + kbase + (size_t)n0 * 128 + l4 * 8;
            const ushort_t* w0l = wsb + WS_WDL + kbase + (size_t)n0 * 128 + l4 * 8;
            const ushort_t* w1h = w0h + 16 * 128;
            const ushort_t* w1l = w0l + 16 * 128;
            floatx4 a00 = {0.f,0.f,0.f,0.f}, a10 = {0.f,0.f,0.f,0.f};
            floatx4 a01 = {0.f,0.f,0.f,0.f}, a11 = {0.f,0.f,0.f,0.f};
            #pragma unroll
            for (int kc = 0; kc < 4; ++kc) {
                bf16x8 b0h = *(const bf16x8*)(w0h + kc * 32);
                bf16x8 b0l = *(const bf16x8*)(w0l + kc * 32);
                bf16x8 b1h = *(const bf16x8*)(w1h + kc * 32);
                bf16x8 b1l = *(const bf16x8*)(w1l + kc * 32);
                a00 = __builtin_amdgcn_mfma_f32_16x16x32_bf16(ahi[0][kc], b0h, a00, 0, 0, 0);
                a00 = __builtin_amdgcn_mfma_f32_16x16x32_bf16(alo[0][kc], b0h, a00, 0, 0, 0);
                a00 = __builtin_amdgcn_mfma_f32_16x16x32_bf16(ahi[0][kc], b0l, a00, 0, 0, 0);
                a10 = __builtin_amdgcn_mfma_f32_16x16x32_bf16(ahi[1][kc], b0h, a10, 0, 0, 0);
                a10 = __builtin_amdgcn_mfma_f32_16x16x32_bf16(alo[1][kc], b0h, a10, 0, 0, 0);
                a10 = __builtin_amdgcn_mfma_f32_16x16x32_bf16(ahi[1][kc], b0l, a10, 0, 0, 0);
                a01 = __builtin_amdgcn_mfma_f32_16x16x32_bf16(ahi[0][kc], b1h, a01, 0, 0, 0);
                a01 = __builtin_amdgcn_mfma_f32_16x16x32_bf16(alo[0][kc], b1h, a01, 0, 0, 0);
                a01 = __builtin_amdgcn_mfma_f32_16x16x32_bf16(ahi[0][kc], b1l, a01, 0, 0, 0);
                a11 = __builtin_amdgcn_mfma_f32_16x16x32_bf16(ahi[1][kc], b1h, a11, 0, 0, 0);
                a11 = __builtin_amdgcn_mfma_f32_16x16x32_bf16(alo[1][kc], b1h, a11, 0, 0, 0);
                a11 = __builtin_amdgcn_mfma_f32_16x16x32_bf16(ahi[1][kc], b1l, a11, 0, 0, 0);
            }
            float bias0 = bd[4 * n0 + kk];
            float bias1 = bd[4 * n1 + kk];
            #pragma unroll
            for (int r = 0; r < 4; ++r) {
                sh_D[(l4 * 4 + r) * D_PITCH + n0]        = a00[r] + bias0;
                sh_D[(16 + l4 * 4 + r) * D_PITCH + n0]   = a10[r] + bias0;
                sh_D[(l4 * 4 + r) * D_PITCH + n1]        = a01[r] + bias1;
                sh_D[(16 + l4 * 4 + r) * D_PITCH + n1]   = a11[r] + bias1;
            }
        }
        __syncthreads();

        // ---- pre[j] = sum_{i>j} z_per[i]*D[i,j] + z_per[j]*d2[j] + b[j] ----
        const bool flip = (kk & 1) != 0;
        float zr[32];   // zr[i] = z_per[i]
        if (flip) {
            #pragma unroll
            for (int ii = 0; ii < 8; ++ii) {
                float4 v = *(const float4*)(sh_z + b * 36 + ii * 4);
                zr[31 - ii * 4] = v.x; zr[30 - ii * 4] = v.y;
                zr[29 - ii * 4] = v.z; zr[28 - ii * 4] = v.w;
            }
        } else {
            #pragma unroll
            for (int ii = 0; ii < 8; ++ii) {
                float4 v = *(const float4*)(sh_z + b * 36 + ii * 4);
                zr[ii * 4 + 0] = v.x; zr[ii * 4 + 1] = v.y;
                zr[ii * 4 + 2] = v.z; zr[ii * 4 + 3] = v.w;
            }
        }
        float s[4];
        #pragma unroll
        for (int q = 0; q < 4; ++q) {
            int j = jqa[q];
            int zidx = flip ? (31 - j) : j;
            s[q] = bpr[q][kk] + sh_z[b * 36 + zidx] * d2r[q][kk];
        }
        #pragma unroll
        for (int i = 1; i < 32; ++i) {
            float zi = zr[i];
            #pragma unroll
            for (int q = 0; q < 4; ++q) {
                if (i > 8 * q) {
                    float d = Drowf[(i << 5) + jqa[q]];
                    float m = (i >= 8 * q + 8) ? zi : ((i > jqa[q]) ? zi : 0.0f);
                    s[q] = fmaf(d, m, s[q]);
                }
            }
        }
        float tq[4], d1v[4];
        #pragma unroll
        for (int q = 0; q < 4; ++q) {
            int j = jqa[q];
            float tt = fast_tanh(s[q]);
            tq[q] = tt;
            sh_t[b * 36 + j] = tt;
            float d1 = d1r[q][kk], d2 = d2r[q][kk];
            d1v[q] = d1;
            float dj = (1.f - tt * tt) * (d1 * d2) + 1.f;
            ld_acc += __logf(fabsf(dj));
        }
        __syncthreads();

        // ---- dz[p] = sum_{j>p} t[j]*D[p,j] + t[p]*d1[p]; z update ----
        float tr[32];
        #pragma unroll
        for (int ii = 0; ii < 8; ++ii) {
            float4 v = *(const float4*)(sh_t + b * 36 + ii * 4);
            tr[ii * 4 + 0] = v.x; tr[ii * 4 + 1] = v.y;
            tr[ii * 4 + 2] = v.z; tr[ii * 4 + 3] = v.w;
        }
        #pragma unroll
        for (int q = 0; q < 4; ++q) {
            int p = jqa[q];
            float dzv = tq[q] * d1v[q];
            #pragma unroll
            for (int blk = 0; blk < 8; ++blk) {
                if (blk >= 2 * q) {            // j <= 8q-1 < p never contributes
                    float4 dv = *(const float4*)(Drowf + (p << 5) + blk * 4);
                    if (blk >= 2 * q + 2) {    // all j >= 8q+8 > p
                        dzv = fmaf(dv.x, tr[blk * 4 + 0], dzv);
                        dzv = fmaf(dv.y, tr[blk * 4 + 1], dzv);
                        dzv = fmaf(dv.z, tr[blk * 4 + 2], dzv);
                        dzv = fmaf(dv.w, tr[blk * 4 + 3], dzv);
                    } else {
                        dzv = fmaf(dv.x, (blk * 4 + 0 > p) ? tr[blk * 4 + 0] : 0.f, dzv);
                        dzv = fmaf(dv.y, (blk * 4 + 1 > p) ? tr[blk * 4 + 1] : 0.f, dzv);
                        dzv = fmaf(dv.z, (blk * 4 + 2 > p) ? tr[blk * 4 + 2] : 0.f, dzv);
                        dzv = fmaf(dv.w, (blk * 4 + 3 > p) ? tr[blk * 4 + 3] : 0.f, dzv);
                    }
                }
            }
            int zidx = flip ? (31 - p) : p;
            sh_z[b * 36 + zidx] += dzv;
        }
        __syncthreads();
    }

    // ---- epilogue: write z and log_det_j ----
    {
        float4 zv = *(const float4*)(sh_z + b * 36 + jl * 4);
        *(float4*)(out + (size_t)(bg0 + b) * ZDIM + jl * 4) = zv;
        float v = ld_acc;
        v += __shfl_xor(v, 1, 8);
        v += __shfl_xor(v, 2, 8);
        v += __shfl_xor(v, 4, 8);
        if (jl == 0) out[(size_t)B_TOTAL * ZDIM + bg0 + b] = v;
    }
}

extern "C" void kernel_launch(void* const* d_in, const int* in_sizes, int n_in,
                              void* d_out, int out_size, void* d_ws, size_t ws_size,
                              hipStream_t stream) {
    const float* z0  = (const float*)d_in[0];
    const float* h   = (const float*)d_in[1];
    const float* Wd  = (const float*)d_in[2];
    const float* bd  = (const float*)d_in[3];
    const float* Wd1 = (const float*)d_in[4];
    const float* bd1 = (const float*)d_in[5];
    const float* Wd2 = (const float*)d_in[6];
    const float* bd2 = (const float*)d_in[7];
    const float* Wb  = (const float*)d_in[8];
    const float* bb  = (const float*)d_in[9];
    ushort_t* ws = (ushort_t*)d_ws;
    float* out = (float*)d_out;

    convert_kernel<<<560, 256, 0, stream>>>(Wd, Wd1, Wd2, Wb, ws);

    (void)hipFuncSetAttribute((const void*)sylv_kernel,
                              hipFuncAttributeMaxDynamicSharedMemorySize, LDS_BYTES);
    sylv_kernel<<<B_TOTAL / TB, 256, LDS_BYTES, stream>>>(ws, h, z0, bd, bd1, bd2, bb, out);
}

// Round 3
// 394.032 us; speedup vs baseline: 1.1208x; 1.1208x over previous
//
#include <hip/hip_runtime.h>

typedef unsigned short ushort_t;
typedef unsigned int uint_t;
typedef __attribute__((ext_vector_type(8))) short bf16x8;
typedef __attribute__((ext_vector_type(4))) float floatx4;

#define ZDIM 32
#define KDIM 4
#define HDIM 128
#define B_TOTAL 32768
#define TB 32

// ws layout (ushort element offsets): Wd hi/lo reordered [k][n][c], Wsm hi/lo [m][n][c]
#define WS_WDH 0
#define WS_WDL 524288
#define WS_SMH 1048576
#define WS_SML 1097728

// LDS layout (byte offsets)
#define D_PITCH   1028        // fp32 elements per batch row; 4b term + diag stagger => <=2-way
#define SH_D_OFF  0           // float [32][1028] = 131584 B
#define AUX_PITCH 132
#define SH_AUX_OFF 0          // float [3][32][132] = 50688 B (pre-loop only, aliases D)
#define SH_HH_OFF 51200       // ushort [32][136] = 8704 B (pre-loop only, aliases D)
#define SH_HL_OFF 59904       // ushort [32][136] = 8704 B (pre-loop only, aliases D)
#define SH_Z_OFF  131584      // float [32][36] = 4608 B
#define SH_T_OFF  136192      // float [32][36] = 4608 B
#define LDS_BYTES 140800

__device__ __forceinline__ ushort_t f2bf(float f) {
    uint_t u = __builtin_bit_cast(uint_t, f);
    u += 0x7FFFu + ((u >> 16) & 1u);
    return (ushort_t)(u >> 16);
}
__device__ __forceinline__ float bf2f(ushort_t s) {
    return __builtin_bit_cast(float, ((uint_t)s) << 16);
}
__device__ __forceinline__ void split1(float x, ushort_t& hi, ushort_t& lo) {
    hi = f2bf(x);
    lo = f2bf(x - bf2f(hi));
}
__device__ __forceinline__ void split4(float4 v, ushort4& hi, ushort4& lo) {
    split1(v.x, hi.x, lo.x); split1(v.y, hi.y, lo.y);
    split1(v.z, hi.z, lo.z); split1(v.w, hi.w, lo.w);
}
__device__ __forceinline__ float fast_tanh(float x) {
    float e = __expf(2.0f * x);
    return 1.0f - 2.0f / (e + 1.0f);
}

// ---------------------------------------------------------------------------
// Kernel 1: split Wd (reordered per-k-slice) and Wd1/Wd2/Wb into bf16 hi/lo.
// ---------------------------------------------------------------------------
__global__ __launch_bounds__(256) void convert_kernel(
    const float* __restrict__ Wd, const float* __restrict__ Wd1,
    const float* __restrict__ Wd2, const float* __restrict__ Wb,
    ushort_t* __restrict__ ws)
{
    int g = blockIdx.x * 256 + threadIdx.x;
    if (g < 131072) {
        int k = g >> 15;            // 32768 float4 per k-slice
        int rem = g & 32767;
        int n = rem >> 5;           // n = i*32+j
        int c4 = rem & 31;
        float4 v = *((const float4*)Wd + (size_t)(4 * n + k) * 32 + c4);
        ushort4 hi, lo; split4(v, hi, lo);
        ((ushort4*)(ws + WS_WDH))[g] = hi;
        ((ushort4*)(ws + WS_WDL))[g] = lo;
    } else {
        int s = g - 131072;         // [0, 12288)
        const float* src = (s < 4096) ? Wd1 : ((s < 8192) ? Wd2 : Wb);
        int r = s & 4095;
        float4 v = ((const float4*)src)[r];
        ushort4 hi, lo; split4(v, hi, lo);
        ((ushort4*)(ws + WS_SMH))[s] = hi;
        ((ushort4*)(ws + WS_SML))[s] = lo;
    }
}

// ---------------------------------------------------------------------------
// Kernel 2: fused split-bf16 encoder GEMMs (fp32-accurate) + K-step flow.
// 512 threads (8 waves/CU), one WG = 32 batches, fp32 D staggered in LDS.
// D element (b, i, j) lives at b*1028 + i*32 + ((i+j)&31): all store/read
// patterns <=2-way bank aliased (free).
// ---------------------------------------------------------------------------
__global__ __launch_bounds__(512, 2) void sylv_kernel(
    const ushort_t* __restrict__ wsb,
    const float* __restrict__ hglob,
    const float* __restrict__ z0,
    const float* __restrict__ bd,
    const float* __restrict__ bd1,
    const float* __restrict__ bd2,
    const float* __restrict__ bb,
    float* __restrict__ out)
{
    extern __shared__ char smem[];
    float*    sh_D   = (float*)(smem + SH_D_OFF);
    float*    sh_aux = (float*)(smem + SH_AUX_OFF);
    ushort_t* sh_hh  = (ushort_t*)(smem + SH_HH_OFF);
    ushort_t* sh_hl  = (ushort_t*)(smem + SH_HL_OFF);
    float*    sh_z   = (float*)(smem + SH_Z_OFF);
    float*    sh_t   = (float*)(smem + SH_T_OFF);

    const int t   = threadIdx.x;
    const int bg0 = blockIdx.x * TB;
    const int lane = t & 63, w = t >> 6;
    const int l15 = lane & 15, l4 = lane >> 4;
    // flow mapping: thread -> (fb, {j2, j2+16}); in-wave fb spacing 2 for
    // conflict-freedom vs D_PITCH=1028 (4*fb + stagger covers banks 2-way)
    const int j2 = t & 15;
    const int bq = (t >> 4) & 3;
    const int fb = (w & 1) | (bq << 1) | ((w >> 1) << 3);

    // ---- stage h (fp32 -> bf16 hi/lo in LDS) and z0 ----
    {
        const float4* hsrc = (const float4*)(hglob + (size_t)bg0 * HDIM);
        #pragma unroll
        for (int it = 0; it < 2; ++it) {
            int c = t + it * 512;       // 1024 float4 chunks
            int row = c >> 5, col4 = c & 31;
            float4 v = hsrc[c];
            ushort4 hi, lo; split4(v, hi, lo);
            *(ushort4*)(sh_hh + row * 136 + col4 * 4) = hi;
            *(ushort4*)(sh_hl + row * 136 + col4 * 4) = lo;
        }
        int zb = t >> 4, zc = t & 15;
        float2 zv = *(const float2*)(z0 + (size_t)(bg0 + zb) * ZDIM + zc * 2);
        *(float2*)(sh_z + zb * 36 + zc * 2) = zv;
    }
    __syncthreads();

    // ---- A fragments (hi and lo): A[m=lane&15][k=(lane>>4)*8+j] ----
    bf16x8 ahi[2][4], alo[2][4];
    #pragma unroll
    for (int mt = 0; mt < 2; ++mt)
        #pragma unroll
        for (int kc = 0; kc < 4; ++kc) {
            ahi[mt][kc] = *(const bf16x8*)(sh_hh + (mt * 16 + l15) * 136 + kc * 32 + l4 * 8);
            alo[mt][kc] = *(const bf16x8*)(sh_hl + (mt * 16 + l15) * 136 + kc * 32 + l4 * 8);
        }

    // ---- small GEMMs (3-pass split): d1, d2, bpre -> aux[m][batch][n] ----
    #pragma unroll
    for (int pi = 0; pi < 3; ++pi) {
        int p = w * 3 + pi;             // 24 jobs over 8 waves
        int m_i = p >> 3, nt = p & 7, n = nt * 16 + l15;
        const ushort_t* wph = wsb + WS_SMH + (size_t)(m_i * 128 + n) * 128 + l4 * 8;
        const ushort_t* wpl = wsb + WS_SML + (size_t)(m_i * 128 + n) * 128 + l4 * 8;
        floatx4 a0 = {0.f, 0.f, 0.f, 0.f}, a1 = {0.f, 0.f, 0.f, 0.f};
        #pragma unroll
        for (int kc = 0; kc < 4; ++kc) {
            bf16x8 bh = *(const bf16x8*)(wph + kc * 32);
            bf16x8 bl = *(const bf16x8*)(wpl + kc * 32);
            a0 = __builtin_amdgcn_mfma_f32_16x16x32_bf16(ahi[0][kc], bh, a0, 0, 0, 0);
            a0 = __builtin_amdgcn_mfma_f32_16x16x32_bf16(alo[0][kc], bh, a0, 0, 0, 0);
            a0 = __builtin_amdgcn_mfma_f32_16x16x32_bf16(ahi[0][kc], bl, a0, 0, 0, 0);
            a1 = __builtin_amdgcn_mfma_f32_16x16x32_bf16(ahi[1][kc], bh, a1, 0, 0, 0);
            a1 = __builtin_amdgcn_mfma_f32_16x16x32_bf16(alo[1][kc], bh, a1, 0, 0, 0);
            a1 = __builtin_amdgcn_mfma_f32_16x16x32_bf16(ahi[1][kc], bl, a1, 0, 0, 0);
        }
        const float* bv = (m_i == 0) ? bd1 : ((m_i == 1) ? bd2 : bb);
        float bias = bv[n];
        float* ap = sh_aux + m_i * (32 * AUX_PITCH) + n;
        #pragma unroll
        for (int r = 0; r < 4; ++r) {
            float v0 = a0[r] + bias, v1 = a1[r] + bias;
            if (m_i < 2) { v0 = fast_tanh(v0); v1 = fast_tanh(v1); }
            ap[(l4 * 4 + r) * AUX_PITCH] = v0;
            ap[(16 + l4 * 4 + r) * AUX_PITCH] = v1;
        }
    }
    __syncthreads();

    // ---- aux -> registers (24 floats/thread), then free the D region ----
    float4 d1a = *(const float4*)(sh_aux + 0 * (32 * AUX_PITCH) + fb * AUX_PITCH + j2 * 4);
    float4 d2a = *(const float4*)(sh_aux + 1 * (32 * AUX_PITCH) + fb * AUX_PITCH + j2 * 4);
    float4 bpa = *(const float4*)(sh_aux + 2 * (32 * AUX_PITCH) + fb * AUX_PITCH + j2 * 4);
    float4 d1b = *(const float4*)(sh_aux + 0 * (32 * AUX_PITCH) + fb * AUX_PITCH + (j2 + 16) * 4);
    float4 d2b = *(const float4*)(sh_aux + 1 * (32 * AUX_PITCH) + fb * AUX_PITCH + (j2 + 16) * 4);
    float4 bpb = *(const float4*)(sh_aux + 2 * (32 * AUX_PITCH) + fb * AUX_PITCH + (j2 + 16) * 4);
    __syncthreads();

    float ld_acc = 0.f;
    float* Db = sh_D + fb * D_PITCH;

    #pragma unroll
    for (int kk = 0; kk < KDIM; ++kk) {
        // ---- GEMM: D_k[b][n] = h@Wd_k^T + bd, fp32 via 3-pass split ----
        const size_t kbase = (size_t)(kk * 1024) * 128;
        #pragma unroll
        for (int g = 0; g < 4; ++g) {
            int nc0 = w * 128 + g * 32 + l15;
            int nc1 = nc0 + 16;
            const ushort_t* w0h = wsb + WS_WDH + kbase + (size_t)nc0 * 128 + l4 * 8;
            const ushort_t* w0l = wsb + WS_WDL + kbase + (size_t)nc0 * 128 + l4 * 8;
            const ushort_t* w1h = w0h + 16 * 128;
            const ushort_t* w1l = w0l + 16 * 128;
            floatx4 a00 = {0.f,0.f,0.f,0.f}, a10 = {0.f,0.f,0.f,0.f};
            floatx4 a01 = {0.f,0.f,0.f,0.f}, a11 = {0.f,0.f,0.f,0.f};
            #pragma unroll
            for (int kc = 0; kc < 4; ++kc) {
                bf16x8 b0h = *(const bf16x8*)(w0h + kc * 32);
                bf16x8 b0l = *(const bf16x8*)(w0l + kc * 32);
                bf16x8 b1h = *(const bf16x8*)(w1h + kc * 32);
                bf16x8 b1l = *(const bf16x8*)(w1l + kc * 32);
                a00 = __builtin_amdgcn_mfma_f32_16x16x32_bf16(ahi[0][kc], b0h, a00, 0, 0, 0);
                a00 = __builtin_amdgcn_mfma_f32_16x16x32_bf16(alo[0][kc], b0h, a00, 0, 0, 0);
                a00 = __builtin_amdgcn_mfma_f32_16x16x32_bf16(ahi[0][kc], b0l, a00, 0, 0, 0);
                a10 = __builtin_amdgcn_mfma_f32_16x16x32_bf16(ahi[1][kc], b0h, a10, 0, 0, 0);
                a10 = __builtin_amdgcn_mfma_f32_16x16x32_bf16(alo[1][kc], b0h, a10, 0, 0, 0);
                a10 = __builtin_amdgcn_mfma_f32_16x16x32_bf16(ahi[1][kc], b0l, a10, 0, 0, 0);
                a01 = __builtin_amdgcn_mfma_f32_16x16x32_bf16(ahi[0][kc], b1h, a01, 0, 0, 0);
                a01 = __builtin_amdgcn_mfma_f32_16x16x32_bf16(alo[0][kc], b1h, a01, 0, 0, 0);
                a01 = __builtin_amdgcn_mfma_f32_16x16x32_bf16(ahi[0][kc], b1l, a01, 0, 0, 0);
                a11 = __builtin_amdgcn_mfma_f32_16x16x32_bf16(ahi[1][kc], b1h, a11, 0, 0, 0);
                a11 = __builtin_amdgcn_mfma_f32_16x16x32_bf16(alo[1][kc], b1h, a11, 0, 0, 0);
                a11 = __builtin_amdgcn_mfma_f32_16x16x32_bf16(ahi[1][kc], b1l, a11, 0, 0, 0);
            }
            int ii = nc0 >> 5;
            int c0 = ((nc0 & 31) + ii) & 31;
            int c1 = ((nc1 & 31) + ii) & 31;
            int base0 = (ii << 5) + c0;
            int base1 = (ii << 5) + c1;
            float bias0 = bd[4 * nc0 + kk];
            float bias1 = bd[4 * nc1 + kk];
            #pragma unroll
            for (int r = 0; r < 4; ++r) {
                sh_D[(l4 * 4 + r) * D_PITCH + base0]      = a00[r] + bias0;
                sh_D[(16 + l4 * 4 + r) * D_PITCH + base0] = a10[r] + bias0;
                sh_D[(l4 * 4 + r) * D_PITCH + base1]      = a01[r] + bias1;
                sh_D[(16 + l4 * 4 + r) * D_PITCH + base1] = a11[r] + bias1;
            }
        }
        __syncthreads();

        // ---- pre[j] = b[j] + z_per[j]*d2[j] + sum_{i>j} z_per[i]*D[i,j] ----
        const bool flip = (kk & 1) != 0;
        const int zj0 = flip ? (31 - j2) : j2;
        const int zj1 = flip ? (15 - j2) : (j2 + 16);
        float s0 = bpa[kk] + sh_z[fb * 36 + zj0] * d2a[kk];
        float s1 = bpb[kk] + sh_z[fb * 36 + zj1] * d2b[kk];
        #pragma unroll
        for (int i = 1; i <= 16; ++i) {       // i <= 16: only j2 (<16) can have i>j
            float zi = sh_z[fb * 36 + (flip ? (31 - i) : i)];
            float dd = Db[(i << 5) + ((i + j2) & 31)];
            s0 = fmaf(dd, (i > j2) ? zi : 0.f, s0);
        }
        #pragma unroll
        for (int i = 17; i < 32; ++i) {       // i >= 17: i > j2 always
            float zi = sh_z[fb * 36 + (flip ? (31 - i) : i)];
            float dd0 = Db[(i << 5) + ((i + j2) & 31)];
            s0 = fmaf(dd0, zi, s0);
            float dd1 = Db[(i << 5) + ((i + j2 + 16) & 31)];
            s1 = fmaf(dd1, (i > j2 + 16) ? zi : 0.f, s1);
        }
        float t0 = fast_tanh(s0), t1 = fast_tanh(s1);
        sh_t[fb * 36 + j2] = t0;
        sh_t[fb * 36 + j2 + 16] = t1;
        float dj0 = (1.f - t0 * t0) * (d1a[kk] * d2a[kk]) + 1.f;
        float dj1 = (1.f - t1 * t1) * (d1b[kk] * d2b[kk]) + 1.f;
        ld_acc += __logf(fabsf(dj0)) + __logf(fabsf(dj1));
        __syncthreads();

        // ---- dz[p] = t[p]*d1[p] + sum_{j>p} t[j]*D[p,j]; z update ----
        float dz0 = t0 * d1a[kk];             // p = j2
        float dz1 = t1 * d1b[kk];             // p = j2+16
        #pragma unroll
        for (int j = 1; j <= 16; ++j) {       // j <= 16: only p=j2 can have j>p
            float tj = sh_t[fb * 36 + j];
            float dd = Db[(j2 << 5) + ((j2 + j) & 31)];
            dz0 = fmaf(dd, (j > j2) ? tj : 0.f, dz0);
        }
        #pragma unroll
        for (int j = 17; j < 32; ++j) {       // j >= 17: j > j2 always
            float tj = sh_t[fb * 36 + j];
            float dd0 = Db[(j2 << 5) + ((j2 + j) & 31)];
            dz0 = fmaf(dd0, tj, dz0);
            float dd1 = Db[((j2 + 16) << 5) + ((j2 + 16 + j) & 31)];
            dz1 = fmaf(dd1, (j > j2 + 16) ? tj : 0.f, dz1);
        }
        sh_z[fb * 36 + zj0] += dz0;
        sh_z[fb * 36 + zj1] += dz1;
        __syncthreads();
    }

    // ---- epilogue: write z and log_det_j ----
    {
        int zb = t >> 4, zc = t & 15;
        float2 zv = *(const float2*)(sh_z + zb * 36 + zc * 2);
        *(float2*)(out + (size_t)(bg0 + zb) * ZDIM + zc * 2) = zv;
        float v = ld_acc;
        v += __shfl_xor(v, 1, 16);
        v += __shfl_xor(v, 2, 16);
        v += __shfl_xor(v, 4, 16);
        v += __shfl_xor(v, 8, 16);
        if (j2 == 0) out[(size_t)B_TOTAL * ZDIM + bg0 + fb] = v;
    }
}

extern "C" void kernel_launch(void* const* d_in, const int* in_sizes, int n_in,
                              void* d_out, int out_size, void* d_ws, size_t ws_size,
                              hipStream_t stream) {
    const float* z0  = (const float*)d_in[0];
    const float* h   = (const float*)d_in[1];
    const float* Wd  = (const float*)d_in[2];
    const float* bd  = (const float*)d_in[3];
    const float* Wd1 = (const float*)d_in[4];
    const float* bd1 = (const float*)d_in[5];
    const float* Wd2 = (const float*)d_in[6];
    const float* bd2 = (const float*)d_in[7];
    const float* Wb  = (const float*)d_in[8];
    const float* bb  = (const float*)d_in[9];
    ushort_t* ws = (ushort_t*)d_ws;
    float* out = (float*)d_out;

    convert_kernel<<<560, 256, 0, stream>>>(Wd, Wd1, Wd2, Wb, ws);

    (void)hipFuncSetAttribute((const void*)sylv_kernel,
                              hipFuncAttributeMaxDynamicSharedMemorySize, LDS_BYTES);
    sylv_kernel<<<B_TOTAL / TB, 512, LDS_BYTES, stream>>>(ws, h, z0, bd, bd1, bd2, bb, out);
}